// Round 2
// baseline (2425.188 us; speedup 1.0000x reference)
//
#include <hip/hip_runtime.h>
#include <math.h>

#define BB 16
#define SS 8192
#define HH 768
#define NH 12
#define HD 64
#define SCALE 0.125f

// ws float offsets (cpb-independent part)
#define WS_QKP   0        // 9216
#define WS_C     9216     // 16
#define WS_GATE  9232     // 768
#define WS_OP    10240    // 16*768 = 12288
#define WS_POOLED 22528   // 16*12*768 = 147456
#define WS_STATS 169984   // pm: 16*cpb*12, pl: 16*cpb*12, then part: 16*cpb*9216

// ---------------- K0: qkp = scale*Wk^T q (+c), gate ----------------
__global__ __launch_bounds__(256) void k_pre(const float* __restrict__ query,
                                             const float* __restrict__ w_kv,
                                             const float* __restrict__ b_kv,
                                             const float* __restrict__ w_gate,
                                             const float* __restrict__ b_gate,
                                             float* __restrict__ ws) {
    int blk = blockIdx.x, t = threadIdx.x;
    if (blk < 36) {
        int h = blk / 3;
        int j = (blk % 3) * 256 + t;
        float acc = 0.f;
        #pragma unroll 8
        for (int d = 0; d < HD; d++)
            acc += query[h * HD + d] * w_kv[(size_t)(h * HD + d) * HH + j];
        ws[WS_QKP + h * HH + j] = acc * SCALE;
    } else if (blk == 36) {
        if (t < NH) {
            float acc = 0.f;
            for (int d = 0; d < HD; d++)
                acc += query[t * HD + d] * b_kv[t * HD + d];
            ws[WS_C + t] = acc * SCALE;
        }
    } else {
        // gate: wave-per-output, coalesced rows
        __shared__ __align__(16) float qs[HH];
        for (int i = t; i < HH; i += 256) qs[i] = query[i];
        __syncthreads();
        int g = blk - 37;                 // 0..11
        int wave = t >> 6, lane = t & 63;
        for (int o = 0; o < 16; o++) {
            int i = g * 64 + wave * 16 + o;
            const float* wr = w_gate + (size_t)i * HH + lane * 4;
            float s = 0.f;
            #pragma unroll
            for (int kk = 0; kk < 3; kk++) {
                float4 wv = *(const float4*)(wr + 256 * kk);
                float4 qv = *(const float4*)&qs[lane * 4 + 256 * kk];
                s += wv.x * qv.x + wv.y * qv.y + wv.z * qv.z + wv.w * qv.w;
            }
            #pragma unroll
            for (int off = 1; off < 64; off <<= 1) s += __shfl_xor(s, off, 64);
            if (lane == 0) {
                float z = s + b_gate[i];
                ws[WS_GATE + i] = 1.0f / (1.0f + expf(-z));
            }
        }
    }
}

// ---------------- K1: fused scores + online softmax + pooling (single x read) ----------------
__global__ __launch_bounds__(256, 3) void k_fused(const float* __restrict__ x,
                                                  const float* __restrict__ ws,
                                                  float* __restrict__ part,
                                                  float* __restrict__ pm,
                                                  float* __restrict__ pl,
                                                  int cpb, int rows) {
    __shared__ __align__(16) float xt[16 * 772];
    __shared__ __align__(16) float st[16][12];
    __shared__ __align__(16) float wt[16][12];
    __shared__ float msh[12], fsh[12], lsh[12];

    int t = threadIdx.x;
    int cblk = blockIdx.x, b = blockIdx.y;
    int lane = t & 63, wave = t >> 6, k = lane & 15, rg = lane >> 4;
    int row = wave * 4 + rg;                 // 0..15 within tile
    const float* qk = ws + WS_QKP;

    float ccv[12];
    #pragma unroll
    for (int h = 0; h < NH; h++) ccv[h] = ws[WS_C + h];

    float P[12][3];
    #pragma unroll
    for (int h = 0; h < NH; h++) { P[h][0] = 0.f; P[h][1] = 0.f; P[h][2] = 0.f; }

    if (t < NH) { msh[t] = -1e30f; lsh[t] = 0.f; }
    __syncthreads();

    int nt = rows >> 4;
    const float* xbase = x + ((size_t)b * SS + (size_t)cblk * rows) * HH;

    for (int tile = 0; tile < nt; tile++) {
        // ---- phase 1: scores for 16 rows (16 lanes per row), stage x-tile to LDS ----
        const float* xr = xbase + (size_t)(tile * 16 + row) * HH + 4 * k;
        float4 xv[12];
        #pragma unroll
        for (int c2 = 0; c2 < 12; c2++) xv[c2] = *(const float4*)(xr + 64 * c2);

        float acc[12];
        #pragma unroll
        for (int h = 0; h < NH; h++) acc[h] = 0.f;
        #pragma unroll
        for (int c2 = 0; c2 < 12; c2++) {
            #pragma unroll
            for (int h = 0; h < NH; h++) {
                float4 qv = *(const float4*)(qk + h * HH + 4 * k + 64 * c2);
                acc[h] += xv[c2].x * qv.x + xv[c2].y * qv.y + xv[c2].z * qv.z + xv[c2].w * qv.w;
            }
        }
        #pragma unroll
        for (int h = 0; h < NH; h++) {
            float v = acc[h];
            v += __shfl_xor(v, 1, 64); v += __shfl_xor(v, 2, 64);
            v += __shfl_xor(v, 4, 64); v += __shfl_xor(v, 8, 64);
            acc[h] = v;
        }
        if (k == 0) {
            #pragma unroll
            for (int h = 0; h < NH; h++) st[row][h] = acc[h] + ccv[h];
        }
        #pragma unroll
        for (int c2 = 0; c2 < 12; c2++)
            *(float4*)&xt[row * 772 + 4 * k + 64 * c2] = xv[c2];
        __syncthreads();

        // ---- stats (a): tile max per head, running-max update ----
        int rr = t & 15, hh = t >> 4;
        if (t < 192) {
            float v = st[rr][hh];
            v = fmaxf(v, __shfl_xor(v, 1, 64)); v = fmaxf(v, __shfl_xor(v, 2, 64));
            v = fmaxf(v, __shfl_xor(v, 4, 64)); v = fmaxf(v, __shfl_xor(v, 8, 64));
            if (rr == 0) {
                float mo = msh[hh];
                float mn = fmaxf(mo, v);
                fsh[hh] = __expf(mo - mn);
                msh[hh] = mn;
            }
        }
        __syncthreads();

        // ---- stats (c): weights + l update ----
        if (t < 192) {
            float w = __expf(st[rr][hh] - msh[hh]);
            wt[rr][hh] = w;
            float sm = w;
            sm += __shfl_xor(sm, 1, 64); sm += __shfl_xor(sm, 2, 64);
            sm += __shfl_xor(sm, 4, 64); sm += __shfl_xor(sm, 8, 64);
            if (rr == 0) lsh[hh] = lsh[hh] * fsh[hh] + sm;
        }
        __syncthreads();

        // ---- phase 2: rescale + accumulate P from LDS tile ----
        {
            float f[12];
            #pragma unroll
            for (int h = 0; h < NH; h++) f[h] = fsh[h];
            #pragma unroll
            for (int h = 0; h < NH; h++) { P[h][0] *= f[h]; P[h][1] *= f[h]; P[h][2] *= f[h]; }
            #pragma unroll
            for (int r = 0; r < 16; r++) {
                float x0 = xt[r * 772 + t];
                float x1 = xt[r * 772 + 256 + t];
                float x2 = xt[r * 772 + 512 + t];
                float wv[12];
                *(float4*)&wv[0] = *(const float4*)&wt[r][0];
                *(float4*)&wv[4] = *(const float4*)&wt[r][4];
                *(float4*)&wv[8] = *(const float4*)&wt[r][8];
                #pragma unroll
                for (int h = 0; h < NH; h++) {
                    P[h][0] += wv[h] * x0;
                    P[h][1] += wv[h] * x1;
                    P[h][2] += wv[h] * x2;
                }
            }
        }
        __syncthreads();
    }

    // write partials
    size_t blkc = (size_t)b * cpb + cblk;
    #pragma unroll
    for (int h = 0; h < NH; h++)
        #pragma unroll
        for (int kk = 0; kk < 3; kk++)
            part[(blkc * NH + h) * HH + kk * 256 + t] = P[h][kk];
    if (t < NH) { pm[blkc * NH + t] = msh[t]; pl[blkc * NH + t] = lsh[t]; }
}

// ---------------- K2: combine chunk partials -> pooled[b][h][col] ----------------
__global__ __launch_bounds__(256) void k_comb(const float* __restrict__ part,
                                              const float* __restrict__ pm,
                                              const float* __restrict__ pl,
                                              float* __restrict__ pooled, int cpb) {
    int h = blockIdx.x, b = blockIdx.y, t = threadIdx.x;
    __shared__ float fac[64];
    __shared__ float Ish;
    float mval = -1e30f, lval = 0.f;
    if (t < cpb) {
        mval = pm[((size_t)b * cpb + t) * NH + h];
        lval = pl[((size_t)b * cpb + t) * NH + h];
    }
    if (t < 64) {
        float m = mval;
        #pragma unroll
        for (int off = 1; off < 64; off <<= 1) m = fmaxf(m, __shfl_xor(m, off, 64));
        float fc = (t < cpb) ? __expf(mval - m) : 0.f;
        fac[t] = fc;
        float l = lval * fc;
        #pragma unroll
        for (int off = 1; off < 64; off <<= 1) l += __shfl_xor(l, off, 64);
        if (t == 0) Ish = 1.0f / l;
    }
    __syncthreads();
    float inv = Ish;
    #pragma unroll
    for (int kk = 0; kk < 3; kk++) {
        int col = kk * 256 + t;
        float s = 0.f;
        for (int c = 0; c < cpb; c++)
            s += part[(((size_t)b * cpb + c) * NH + h) * HH + col] * fac[c];
        pooled[((size_t)b * NH + h) * HH + col] = s * inv;
    }
}

// ---------------- K3: op[b][hd] = W_v pooled + b_v ----------------
__global__ __launch_bounds__(256) void k_v(const float* __restrict__ pooled,
                                           const float* __restrict__ w_kv,
                                           const float* __restrict__ b_kv,
                                           float* __restrict__ op) {
    int seg = blockIdx.x, b = blockIdx.y, t = threadIdx.x;
    __shared__ __align__(16) float pv[1536];
    for (int i = t; i < 1536; i += 256)
        pv[i] = pooled[((size_t)b * NH + seg * 2) * HH + i];
    __syncthreads();
    int wave = t >> 6, lane = t & 63;
    int lh = wave >> 1;                      // 0 or 1
    for (int o = 0; o < 32; o++) {
        int hd = seg * 128 + wave * 32 + o;
        const float* wr = w_kv + (size_t)(HH + hd) * HH + lane * 4;
        float s = 0.f;
        #pragma unroll
        for (int kk = 0; kk < 3; kk++) {
            float4 wv = *(const float4*)(wr + 256 * kk);
            float4 qv = *(const float4*)&pv[lh * HH + lane * 4 + 256 * kk];
            s += wv.x * qv.x + wv.y * qv.y + wv.z * qv.z + wv.w * qv.w;
        }
        #pragma unroll
        for (int off = 1; off < 64; off <<= 1) s += __shfl_xor(s, off, 64);
        if (lane == 0) op[(size_t)b * HH + hd] = s + b_kv[HH + hd];
    }
}

// ---------------- K4: out = gate * (W_out op + b_out) ----------------
__global__ __launch_bounds__(256) void k_fin(const float* __restrict__ op_in,
                                             const float* __restrict__ w_out,
                                             const float* __restrict__ b_out,
                                             const float* __restrict__ gate,
                                             float* __restrict__ out) {
    int seg = blockIdx.x, b = blockIdx.y, t = threadIdx.x;
    __shared__ __align__(16) float ov[HH];
    for (int i = t; i < HH; i += 256) ov[i] = op_in[(size_t)b * HH + i];
    __syncthreads();
    int wave = t >> 6, lane = t & 63;
    for (int o = 0; o < 32; o++) {
        int i = seg * 128 + wave * 32 + o;
        const float* wr = w_out + (size_t)i * HH + lane * 4;
        float s = 0.f;
        #pragma unroll
        for (int kk = 0; kk < 3; kk++) {
            float4 wv = *(const float4*)(wr + 256 * kk);
            float4 qv = *(const float4*)&ov[lane * 4 + 256 * kk];
            s += wv.x * qv.x + wv.y * qv.y + wv.z * qv.z + wv.w * qv.w;
        }
        #pragma unroll
        for (int off = 1; off < 64; off <<= 1) s += __shfl_xor(s, off, 64);
        if (lane == 0) out[(size_t)b * HH + i] = gate[i] * (s + b_out[i]);
    }
}

extern "C" void kernel_launch(void* const* d_in, const int* in_sizes, int n_in,
                              void* d_out, int out_size, void* d_ws, size_t ws_size,
                              hipStream_t stream) {
    const float* x      = (const float*)d_in[0];
    const float* query  = (const float*)d_in[1];
    const float* w_kv   = (const float*)d_in[2];
    const float* b_kv   = (const float*)d_in[3];
    const float* w_out  = (const float*)d_in[4];
    const float* b_out  = (const float*)d_in[5];
    const float* w_gate = (const float*)d_in[6];
    const float* b_gate = (const float*)d_in[7];
    float* ws  = (float*)d_ws;
    float* out = (float*)d_out;

    // choose chunks-per-batch by available workspace
    size_t need64 = ((size_t)WS_STATS + 2 * (size_t)BB * 64 * NH + (size_t)BB * 64 * NH * HH) * 4;
    int cpb = (ws_size >= need64) ? 64 : 32;
    int rows = SS / cpb;

    float* gate   = ws + WS_GATE;
    float* opbuf  = ws + WS_OP;
    float* pooled = ws + WS_POOLED;
    float* pm     = ws + WS_STATS;
    float* pl     = pm + (size_t)BB * cpb * NH;
    float* part   = pl + (size_t)BB * cpb * NH;

    k_pre<<<49, 256, 0, stream>>>(query, w_kv, b_kv, w_gate, b_gate, ws);
    k_fused<<<dim3(cpb, BB), 256, 0, stream>>>(x, ws, part, pm, pl, cpb, rows);
    k_comb<<<dim3(NH, BB), 256, 0, stream>>>(part, pm, pl, pooled, cpb);
    k_v<<<dim3(6, BB), 256, 0, stream>>>(pooled, w_kv, b_kv, opbuf);
    k_fin<<<dim3(6, BB), 256, 0, stream>>>(opbuf, w_out, b_out, gate, out);
}

// Round 3
// 534.247 us; speedup vs baseline: 4.5395x; 4.5395x over previous
//
#include <hip/hip_runtime.h>
#include <math.h>

#define BB 16
#define SS 8192
#define HH 768
#define NH 12
#define HD 64
#define SCALE 0.125f

// ws float offsets
#define WS_QKP   0        // 9216
#define WS_C     9216     // 16
#define WS_GATE  9232     // 768
#define WS_OP    10240    // 16*768
#define WS_POOLED 22528   // 16*12*768
#define WS_STATS 169984   // pm[16*cpb*12], pl[16*cpb*12], part[16*cpb*9216]

// ---------------- K0: qkp = scale*Wk^T q (+c), gate ----------------
__global__ __launch_bounds__(256) void k_pre(const float* __restrict__ query,
                                             const float* __restrict__ w_kv,
                                             const float* __restrict__ b_kv,
                                             const float* __restrict__ w_gate,
                                             const float* __restrict__ b_gate,
                                             float* __restrict__ ws) {
    int blk = blockIdx.x, t = threadIdx.x;
    if (blk < 36) {
        int h = blk / 3;
        int j = (blk % 3) * 256 + t;
        float acc = 0.f;
        #pragma unroll 8
        for (int d = 0; d < HD; d++)
            acc += query[h * HD + d] * w_kv[(size_t)(h * HD + d) * HH + j];
        ws[WS_QKP + h * HH + j] = acc * SCALE;
    } else if (blk == 36) {
        if (t < NH) {
            float acc = 0.f;
            for (int d = 0; d < HD; d++)
                acc += query[t * HD + d] * b_kv[t * HD + d];
            ws[WS_C + t] = acc * SCALE;
        }
    } else {
        __shared__ __align__(16) float qs[HH];
        for (int i = t; i < HH; i += 256) qs[i] = query[i];
        __syncthreads();
        int g = blk - 37;
        int wave = t >> 6, lane = t & 63;
        for (int o = 0; o < 16; o++) {
            int i = g * 64 + wave * 16 + o;
            const float* wr = w_gate + (size_t)i * HH + lane * 4;
            float s = 0.f;
            #pragma unroll
            for (int kk = 0; kk < 3; kk++) {
                float4 wv = *(const float4*)(wr + 256 * kk);
                float4 qv = *(const float4*)&qs[lane * 4 + 256 * kk];
                s += wv.x * qv.x + wv.y * qv.y + wv.z * qv.z + wv.w * qv.w;
            }
            #pragma unroll
            for (int off = 1; off < 64; off <<= 1) s += __shfl_xor(s, off, 64);
            if (lane == 0) {
                float z = s + b_gate[i];
                ws[WS_GATE + i] = 1.0f / (1.0f + expf(-z));
            }
        }
    }
}

// ---------------- K1: fused scores + online softmax + pool; x read once from HBM ----------------
__global__ __launch_bounds__(256, 4) void k_fused(const float* __restrict__ x,
                                                  const float* __restrict__ ws,
                                                  float* __restrict__ part,
                                                  float* __restrict__ pm,
                                                  float* __restrict__ pl,
                                                  int cpb, int rows) {
    __shared__ __align__(16) float qkp_s[NH * HH];   // 36 KB
    __shared__ float st[16][NH];
    __shared__ float wt[16][NH];
    __shared__ float msh[NH], fsh[NH], lsh[NH], csh[NH];

    int t = threadIdx.x;
    int cblk = blockIdx.x, b = blockIdx.y;
    int lane = t & 63, wave = t >> 6, k = lane & 15, rg = lane >> 4;
    int row = wave * 4 + rg;                 // 0..15 in tile

    // stage qkp to LDS (coalesced float4)
    {
        const float4* qg = (const float4*)(ws + WS_QKP);
        float4* qs = (float4*)qkp_s;
        #pragma unroll
        for (int i = 0; i < 9; i++) qs[t + 256 * i] = qg[t + 256 * i];
    }
    if (t < NH) { csh[t] = ws[WS_C + t]; msh[t] = -1e30f; lsh[t] = 0.f; }
    __syncthreads();

    float P[NH][3];
    #pragma unroll
    for (int h = 0; h < NH; h++) { P[h][0] = 0.f; P[h][1] = 0.f; P[h][2] = 0.f; }

    int nt = rows >> 4;
    const float* xb = x + ((size_t)b * SS + (size_t)cblk * rows) * HH;

    for (int tile = 0; tile < nt; tile++) {
        // ---- phase 1: scores for 16 rows; 16 lanes per row; x from global, qkp from LDS ----
        {
            const float* xr = xb + (size_t)(tile * 16 + row) * HH + 4 * k;
            float acc[NH];
            #pragma unroll
            for (int h = 0; h < NH; h++) acc[h] = 0.f;
            #pragma unroll
            for (int c2 = 0; c2 < 12; c2++) {
                float4 xq = *(const float4*)(xr + 64 * c2);
                #pragma unroll
                for (int h = 0; h < NH; h++) {
                    float4 qv = *(const float4*)&qkp_s[h * HH + 4 * k + 64 * c2];
                    acc[h] += xq.x * qv.x + xq.y * qv.y + xq.z * qv.z + xq.w * qv.w;
                }
            }
            #pragma unroll
            for (int h = 0; h < NH; h++) {
                float v = acc[h];
                v += __shfl_xor(v, 1, 64); v += __shfl_xor(v, 2, 64);
                v += __shfl_xor(v, 4, 64); v += __shfl_xor(v, 8, 64);
                acc[h] = v;
            }
            if (k == 0) {
                #pragma unroll
                for (int h = 0; h < NH; h++) st[row][h] = acc[h] + csh[h];
            }
        }
        __syncthreads();

        // ---- stats: tile max, running max/f/l, weights (3 waves; same-wave ordering) ----
        if (t < 192) {
            int rr = t & 15, hh = t >> 4;
            float v = st[rr][hh];
            float m4 = v;
            m4 = fmaxf(m4, __shfl_xor(m4, 1, 64)); m4 = fmaxf(m4, __shfl_xor(m4, 2, 64));
            m4 = fmaxf(m4, __shfl_xor(m4, 4, 64)); m4 = fmaxf(m4, __shfl_xor(m4, 8, 64));
            float mo = msh[hh];
            float mn = fmaxf(mo, m4);
            float f  = __expf(mo - mn);
            float w  = __expf(v - mn);
            wt[rr][hh] = w;
            float sm = w;
            sm += __shfl_xor(sm, 1, 64); sm += __shfl_xor(sm, 2, 64);
            sm += __shfl_xor(sm, 4, 64); sm += __shfl_xor(sm, 8, 64);
            if (rr == 0) {
                msh[hh] = mn;
                fsh[hh] = f;
                lsh[hh] = lsh[hh] * f + sm;
            }
        }
        __syncthreads();

        // ---- phase 2: rescale P, accumulate pool from x (L1/L2-hot re-read) ----
        {
            #pragma unroll
            for (int h = 0; h < NH; h++) {
                float fh = fsh[h];
                P[h][0] *= fh; P[h][1] *= fh; P[h][2] *= fh;
            }
            const float* xp = xb + (size_t)(tile * 16) * HH;
            #pragma unroll 4
            for (int r = 0; r < 16; r++) {
                float x0 = xp[(size_t)r * HH + t];
                float x1 = xp[(size_t)r * HH + 256 + t];
                float x2 = xp[(size_t)r * HH + 512 + t];
                #pragma unroll
                for (int h = 0; h < NH; h++) {
                    float wv = wt[r][h];
                    P[h][0] += wv * x0; P[h][1] += wv * x1; P[h][2] += wv * x2;
                }
            }
        }
        __syncthreads();
    }

    // write partials
    size_t blkc = (size_t)b * cpb + cblk;
    #pragma unroll
    for (int h = 0; h < NH; h++) {
        part[(blkc * NH + h) * HH + 0 * 256 + t] = P[h][0];
        part[(blkc * NH + h) * HH + 1 * 256 + t] = P[h][1];
        part[(blkc * NH + h) * HH + 2 * 256 + t] = P[h][2];
    }
    if (t < NH) { pm[blkc * NH + t] = msh[t]; pl[blkc * NH + t] = lsh[t]; }
}

// ---------------- K2: combine chunk partials -> pooled ----------------
__global__ __launch_bounds__(256) void k_comb(const float* __restrict__ part,
                                              const float* __restrict__ pm,
                                              const float* __restrict__ pl,
                                              float* __restrict__ pooled, int cpb) {
    int h = blockIdx.x, b = blockIdx.y, t = threadIdx.x;
    __shared__ float fac[64];
    __shared__ float Ish;
    float mval = -1e30f, lval = 0.f;
    if (t < cpb) {
        mval = pm[((size_t)b * cpb + t) * NH + h];
        lval = pl[((size_t)b * cpb + t) * NH + h];
    }
    if (t < 64) {
        float m = mval;
        #pragma unroll
        for (int off = 1; off < 64; off <<= 1) m = fmaxf(m, __shfl_xor(m, off, 64));
        float fc = (t < cpb) ? __expf(mval - m) : 0.f;
        fac[t] = fc;
        float l = lval * fc;
        #pragma unroll
        for (int off = 1; off < 64; off <<= 1) l += __shfl_xor(l, off, 64);
        if (t == 0) Ish = 1.0f / l;
    }
    __syncthreads();
    float inv = Ish;
    #pragma unroll
    for (int kk = 0; kk < 3; kk++) {
        int col = kk * 256 + t;
        float s = 0.f;
        for (int c = 0; c < cpb; c++)
            s += part[(((size_t)b * cpb + c) * NH + h) * HH + col] * fac[c];
        pooled[((size_t)b * NH + h) * HH + col] = s * inv;
    }
}

// ---------------- K3: op = W_v pooled + b_v ----------------
__global__ __launch_bounds__(256) void k_v(const float* __restrict__ pooled,
                                           const float* __restrict__ w_kv,
                                           const float* __restrict__ b_kv,
                                           float* __restrict__ op) {
    int seg = blockIdx.x, b = blockIdx.y, t = threadIdx.x;
    __shared__ __align__(16) float pv[1536];
    for (int i = t; i < 1536; i += 256)
        pv[i] = pooled[((size_t)b * NH + seg * 2) * HH + i];
    __syncthreads();
    int wave = t >> 6, lane = t & 63;
    int lh = wave >> 1;
    for (int o = 0; o < 32; o++) {
        int hd = seg * 128 + wave * 32 + o;
        const float* wr = w_kv + (size_t)(HH + hd) * HH + lane * 4;
        float s = 0.f;
        #pragma unroll
        for (int kk = 0; kk < 3; kk++) {
            float4 wv = *(const float4*)(wr + 256 * kk);
            float4 qv = *(const float4*)&pv[lh * HH + lane * 4 + 256 * kk];
            s += wv.x * qv.x + wv.y * qv.y + wv.z * qv.z + wv.w * qv.w;
        }
        #pragma unroll
        for (int off = 1; off < 64; off <<= 1) s += __shfl_xor(s, off, 64);
        if (lane == 0) op[(size_t)b * HH + hd] = s + b_kv[HH + hd];
    }
}

// ---------------- K4: out = gate * (W_out op + b_out) ----------------
__global__ __launch_bounds__(256) void k_fin(const float* __restrict__ op_in,
                                             const float* __restrict__ w_out,
                                             const float* __restrict__ b_out,
                                             const float* __restrict__ gate,
                                             float* __restrict__ out) {
    int seg = blockIdx.x, b = blockIdx.y, t = threadIdx.x;
    __shared__ __align__(16) float ov[HH];
    for (int i = t; i < HH; i += 256) ov[i] = op_in[(size_t)b * HH + i];
    __syncthreads();
    int wave = t >> 6, lane = t & 63;
    for (int o = 0; o < 32; o++) {
        int i = seg * 128 + wave * 32 + o;
        const float* wr = w_out + (size_t)i * HH + lane * 4;
        float s = 0.f;
        #pragma unroll
        for (int kk = 0; kk < 3; kk++) {
            float4 wv = *(const float4*)(wr + 256 * kk);
            float4 qv = *(const float4*)&ov[lane * 4 + 256 * kk];
            s += wv.x * qv.x + wv.y * qv.y + wv.z * qv.z + wv.w * qv.w;
        }
        #pragma unroll
        for (int off = 1; off < 64; off <<= 1) s += __shfl_xor(s, off, 64);
        if (lane == 0) out[(size_t)b * HH + i] = gate[i] * (s + b_out[i]);
    }
}

extern "C" void kernel_launch(void* const* d_in, const int* in_sizes, int n_in,
                              void* d_out, int out_size, void* d_ws, size_t ws_size,
                              hipStream_t stream) {
    const float* x      = (const float*)d_in[0];
    const float* query  = (const float*)d_in[1];
    const float* w_kv   = (const float*)d_in[2];
    const float* b_kv   = (const float*)d_in[3];
    const float* w_out  = (const float*)d_in[4];
    const float* b_out  = (const float*)d_in[5];
    const float* w_gate = (const float*)d_in[6];
    const float* b_gate = (const float*)d_in[7];
    float* ws  = (float*)d_ws;
    float* out = (float*)d_out;

    size_t need64 = ((size_t)WS_STATS + 2 * (size_t)BB * 64 * NH + (size_t)BB * 64 * NH * HH) * 4;
    int cpb = (ws_size >= need64) ? 64 : 32;
    int rows = SS / cpb;

    float* gate   = ws + WS_GATE;
    float* opbuf  = ws + WS_OP;
    float* pooled = ws + WS_POOLED;
    float* pm     = ws + WS_STATS;
    float* pl     = pm + (size_t)BB * cpb * NH;
    float* part   = pl + (size_t)BB * cpb * NH;

    k_pre<<<49, 256, 0, stream>>>(query, w_kv, b_kv, w_gate, b_gate, ws);
    k_fused<<<dim3(cpb, BB), 256, 0, stream>>>(x, ws, part, pm, pl, cpb, rows);
    k_comb<<<dim3(NH, BB), 256, 0, stream>>>(part, pm, pl, pooled, cpb);
    k_v<<<dim3(6, BB), 256, 0, stream>>>(pooled, w_kv, b_kv, opbuf);
    k_fin<<<dim3(6, BB), 256, 0, stream>>>(opbuf, w_out, b_out, gate, out);
}

// Round 4
// 430.041 us; speedup vs baseline: 5.6394x; 1.2423x over previous
//
#include <hip/hip_runtime.h>
#include <math.h>

#define BB 16
#define SS 8192
#define HH 768
#define NH 12
#define HD 64
#define SCALE 0.125f
#define CPB 48           // chunks per batch: 32 chunks x 11 tiles + 16 x 10 = 512 tiles of 16 rows

// ws float offsets
#define WS_QKP   0        // 9216
#define WS_C     9216     // 16
#define WS_GATE  9232     // 768
#define WS_OP    10240    // 16*768
#define WS_POOLED 22528   // 16*12*768
#define WS_STATS 169984   // pm[16*CPB*12], pl[16*CPB*12], part[16*CPB*9216]

// ---------------- K0: qkp = scale*Wk^T q (+c), gate ----------------
__global__ __launch_bounds__(256) void k_pre(const float* __restrict__ query,
                                             const float* __restrict__ w_kv,
                                             const float* __restrict__ b_kv,
                                             const float* __restrict__ w_gate,
                                             const float* __restrict__ b_gate,
                                             float* __restrict__ ws) {
    int blk = blockIdx.x, t = threadIdx.x;
    if (blk < 36) {
        int h = blk / 3;
        int j = (blk % 3) * 256 + t;
        float acc = 0.f;
        #pragma unroll 8
        for (int d = 0; d < HD; d++)
            acc += query[h * HD + d] * w_kv[(size_t)(h * HD + d) * HH + j];
        ws[WS_QKP + h * HH + j] = acc * SCALE;
    } else if (blk == 36) {
        if (t < NH) {
            float acc = 0.f;
            for (int d = 0; d < HD; d++)
                acc += query[t * HD + d] * b_kv[t * HD + d];
            ws[WS_C + t] = acc * SCALE;
        }
    } else {
        __shared__ __align__(16) float qs[HH];
        for (int i = t; i < HH; i += 256) qs[i] = query[i];
        __syncthreads();
        int g = blk - 37;
        int wave = t >> 6, lane = t & 63;
        for (int o = 0; o < 16; o++) {
            int i = g * 64 + wave * 16 + o;
            const float* wr = w_gate + (size_t)i * HH + lane * 4;
            float s = 0.f;
            #pragma unroll
            for (int kk = 0; kk < 3; kk++) {
                float4 wv = *(const float4*)(wr + 256 * kk);
                float4 qv = *(const float4*)&qs[lane * 4 + 256 * kk];
                s += wv.x * qv.x + wv.y * qv.y + wv.z * qv.z + wv.w * qv.w;
            }
            #pragma unroll
            for (int off = 1; off < 64; off <<= 1) s += __shfl_xor(s, off, 64);
            if (lane == 0) {
                float z = s + b_gate[i];
                ws[WS_GATE + i] = 1.0f / (1.0f + expf(-z));
            }
        }
    }
}

// ---------------- K1: fused scores + online softmax + pool; x from HBM once ----------------
__global__ __launch_bounds__(256, 3) void k_fused(const float* __restrict__ x,
                                                  const float* __restrict__ ws,
                                                  float* __restrict__ part,
                                                  float* __restrict__ pm,
                                                  float* __restrict__ pl) {
    __shared__ __align__(16) float xt[16 * 772];     // 49.4 KB x-tile (772 pad)
    __shared__ float st[16][NH];
    __shared__ float wt[16][NH];
    __shared__ float msh[NH], fsh[NH], lsh[NH], csh[NH];

    int t = threadIdx.x;
    int cblk = blockIdx.x, b = blockIdx.y;
    int lane = t & 63, wave = t >> 6, k = lane & 15, rg = lane >> 4;
    int row = wave * 4 + rg;                 // 0..15 in tile
    const float* qk = ws + WS_QKP;           // stays in L1/L2 (36 KB, read-only)

    if (t < NH) { csh[t] = ws[WS_C + t]; msh[t] = -1e30f; lsh[t] = 0.f; }
    __syncthreads();

    float P[NH][3];
    #pragma unroll
    for (int h = 0; h < NH; h++) { P[h][0] = 0.f; P[h][1] = 0.f; P[h][2] = 0.f; }

    int nt    = (cblk < 32) ? 11 : 10;
    int tile0 = (cblk < 32) ? cblk * 11 : 352 + (cblk - 32) * 10;
    const float* xb = x + ((size_t)b * SS + (size_t)tile0 * 16) * HH;

    for (int tile = 0; tile < nt; tile++) {
        // ---- phase 1: scores (16 lanes/row); x global -> regs -> LDS tile; qkp via L1/L2 ----
        {
            const float* xr = xb + (size_t)(tile * 16 + row) * HH + 4 * k;
            float acc[NH];
            #pragma unroll
            for (int h = 0; h < NH; h++) acc[h] = 0.f;
            #pragma unroll 4
            for (int c2 = 0; c2 < 12; c2++) {
                float4 xq = *(const float4*)(xr + 64 * c2);
                #pragma unroll
                for (int h = 0; h < NH; h++) {
                    float4 qv = *(const float4*)(qk + h * HH + 4 * k + 64 * c2);
                    acc[h] += xq.x * qv.x + xq.y * qv.y + xq.z * qv.z + xq.w * qv.w;
                }
                *(float4*)&xt[row * 772 + 4 * k + 64 * c2] = xq;
            }
            #pragma unroll
            for (int h = 0; h < NH; h++) {
                float v = acc[h];
                v += __shfl_xor(v, 1, 64); v += __shfl_xor(v, 2, 64);
                v += __shfl_xor(v, 4, 64); v += __shfl_xor(v, 8, 64);
                acc[h] = v;
            }
            if (k == 0) {
                #pragma unroll
                for (int h = 0; h < NH; h++) st[row][h] = acc[h] + csh[h];
            }
        }
        __syncthreads();

        // ---- stats: tile max, running max/f/l, weights ----
        if (t < 192) {
            int rr = t & 15, hh = t >> 4;
            float v = st[rr][hh];
            float m4 = v;
            m4 = fmaxf(m4, __shfl_xor(m4, 1, 64)); m4 = fmaxf(m4, __shfl_xor(m4, 2, 64));
            m4 = fmaxf(m4, __shfl_xor(m4, 4, 64)); m4 = fmaxf(m4, __shfl_xor(m4, 8, 64));
            float mo = msh[hh];
            float mn = fmaxf(mo, m4);
            float f  = __expf(mo - mn);
            float w  = __expf(v - mn);
            wt[rr][hh] = w;
            float sm = w;
            sm += __shfl_xor(sm, 1, 64); sm += __shfl_xor(sm, 2, 64);
            sm += __shfl_xor(sm, 4, 64); sm += __shfl_xor(sm, 8, 64);
            if (rr == 0) {
                msh[hh] = mn;
                fsh[hh] = f;
                lsh[hh] = lsh[hh] * f + sm;
            }
        }
        __syncthreads();

        // ---- phase 2: rescale P, accumulate pool from LDS tile (conflict-free b32 cols) ----
        {
            #pragma unroll
            for (int h = 0; h < NH; h++) {
                float fh = fsh[h];
                P[h][0] *= fh; P[h][1] *= fh; P[h][2] *= fh;
            }
            #pragma unroll 4
            for (int r = 0; r < 16; r++) {
                float x0 = xt[r * 772 + t];
                float x1 = xt[r * 772 + 256 + t];
                float x2 = xt[r * 772 + 512 + t];
                #pragma unroll
                for (int h = 0; h < NH; h++) {
                    float wv = wt[r][h];
                    P[h][0] += wv * x0; P[h][1] += wv * x1; P[h][2] += wv * x2;
                }
            }
        }
        __syncthreads();
    }

    // write partials
    size_t blkc = (size_t)b * CPB + cblk;
    #pragma unroll
    for (int h = 0; h < NH; h++) {
        part[(blkc * NH + h) * HH + 0 * 256 + t] = P[h][0];
        part[(blkc * NH + h) * HH + 1 * 256 + t] = P[h][1];
        part[(blkc * NH + h) * HH + 2 * 256 + t] = P[h][2];
    }
    if (t < NH) { pm[blkc * NH + t] = msh[t]; pl[blkc * NH + t] = lsh[t]; }
}

// ---------------- K2: combine chunk partials -> pooled ----------------
__global__ __launch_bounds__(256) void k_comb(const float* __restrict__ part,
                                              const float* __restrict__ pm,
                                              const float* __restrict__ pl,
                                              float* __restrict__ pooled) {
    int h = blockIdx.x, b = blockIdx.y, t = threadIdx.x;
    __shared__ float fac[64];
    __shared__ float Ish;
    float mval = -1e30f, lval = 0.f;
    if (t < CPB) {
        mval = pm[((size_t)b * CPB + t) * NH + h];
        lval = pl[((size_t)b * CPB + t) * NH + h];
    }
    if (t < 64) {
        float m = mval;
        #pragma unroll
        for (int off = 1; off < 64; off <<= 1) m = fmaxf(m, __shfl_xor(m, off, 64));
        float fc = (t < CPB) ? __expf(mval - m) : 0.f;
        fac[t] = fc;
        float l = lval * fc;
        #pragma unroll
        for (int off = 1; off < 64; off <<= 1) l += __shfl_xor(l, off, 64);
        if (t == 0) Ish = 1.0f / l;
    }
    __syncthreads();
    float inv = Ish;
    #pragma unroll
    for (int kk = 0; kk < 3; kk++) {
        int col = kk * 256 + t;
        float s = 0.f;
        for (int c = 0; c < CPB; c++)
            s += part[(((size_t)b * CPB + c) * NH + h) * HH + col] * fac[c];
        pooled[((size_t)b * NH + h) * HH + col] = s * inv;
    }
}

// ---------------- K3: op = W_v pooled + b_v ----------------
__global__ __launch_bounds__(256) void k_v(const float* __restrict__ pooled,
                                           const float* __restrict__ w_kv,
                                           const float* __restrict__ b_kv,
                                           float* __restrict__ op) {
    int seg = blockIdx.x, b = blockIdx.y, t = threadIdx.x;
    __shared__ __align__(16) float pv[1536];
    for (int i = t; i < 1536; i += 256)
        pv[i] = pooled[((size_t)b * NH + seg * 2) * HH + i];
    __syncthreads();
    int wave = t >> 6, lane = t & 63;
    int lh = wave >> 1;
    for (int o = 0; o < 32; o++) {
        int hd = seg * 128 + wave * 32 + o;
        const float* wr = w_kv + (size_t)(HH + hd) * HH + lane * 4;
        float s = 0.f;
        #pragma unroll
        for (int kk = 0; kk < 3; kk++) {
            float4 wv = *(const float4*)(wr + 256 * kk);
            float4 qv = *(const float4*)&pv[lh * HH + lane * 4 + 256 * kk];
            s += wv.x * qv.x + wv.y * qv.y + wv.z * qv.z + wv.w * qv.w;
        }
        #pragma unroll
        for (int off = 1; off < 64; off <<= 1) s += __shfl_xor(s, off, 64);
        if (lane == 0) op[(size_t)b * HH + hd] = s + b_kv[HH + hd];
    }
}

// ---------------- K4: out = gate * (W_out op + b_out) ----------------
__global__ __launch_bounds__(256) void k_fin(const float* __restrict__ op_in,
                                             const float* __restrict__ w_out,
                                             const float* __restrict__ b_out,
                                             const float* __restrict__ gate,
                                             float* __restrict__ out) {
    int seg = blockIdx.x, b = blockIdx.y, t = threadIdx.x;
    __shared__ __align__(16) float ov[HH];
    for (int i = t; i < HH; i += 256) ov[i] = op_in[(size_t)b * HH + i];
    __syncthreads();
    int wave = t >> 6, lane = t & 63;
    for (int o = 0; o < 32; o++) {
        int i = seg * 128 + wave * 32 + o;
        const float* wr = w_out + (size_t)i * HH + lane * 4;
        float s = 0.f;
        #pragma unroll
        for (int kk = 0; kk < 3; kk++) {
            float4 wv = *(const float4*)(wr + 256 * kk);
            float4 qv = *(const float4*)&ov[lane * 4 + 256 * kk];
            s += wv.x * qv.x + wv.y * qv.y + wv.z * qv.z + wv.w * qv.w;
        }
        #pragma unroll
        for (int off = 1; off < 64; off <<= 1) s += __shfl_xor(s, off, 64);
        if (lane == 0) out[(size_t)b * HH + i] = gate[i] * (s + b_out[i]);
    }
}

extern "C" void kernel_launch(void* const* d_in, const int* in_sizes, int n_in,
                              void* d_out, int out_size, void* d_ws, size_t ws_size,
                              hipStream_t stream) {
    const float* x      = (const float*)d_in[0];
    const float* query  = (const float*)d_in[1];
    const float* w_kv   = (const float*)d_in[2];
    const float* b_kv   = (const float*)d_in[3];
    const float* w_out  = (const float*)d_in[4];
    const float* b_out  = (const float*)d_in[5];
    const float* w_gate = (const float*)d_in[6];
    const float* b_gate = (const float*)d_in[7];
    float* ws  = (float*)d_ws;
    float* out = (float*)d_out;

    float* gate   = ws + WS_GATE;
    float* opbuf  = ws + WS_OP;
    float* pooled = ws + WS_POOLED;
    float* pm     = ws + WS_STATS;
    float* pl     = pm + (size_t)BB * CPB * NH;
    float* part   = pl + (size_t)BB * CPB * NH;

    k_pre<<<49, 256, 0, stream>>>(query, w_kv, b_kv, w_gate, b_gate, ws);
    k_fused<<<dim3(CPB, BB), 256, 0, stream>>>(x, ws, part, pm, pl);
    k_comb<<<dim3(NH, BB), 256, 0, stream>>>(part, pm, pl, pooled);
    k_v<<<dim3(6, BB), 256, 0, stream>>>(pooled, w_kv, b_kv, opbuf);
    k_fin<<<dim3(6, BB), 256, 0, stream>>>(opbuf, w_out, b_out, gate, out);
}